// Round 7
// baseline (83.350 us; speedup 1.0000x reference)
//
#include <hip/hip_runtime.h>

static constexpr int E = 256;
static constexpr int S = 4096;

typedef __attribute__((ext_vector_type(8))) short short8v;   // 8 bf16 (4 VGPRs)
typedef __attribute__((ext_vector_type(4))) float f32x4;     // 4 fp32 acc

static __device__ __forceinline__ unsigned short f2bf(float f) {
    union { float f; unsigned u; } v; v.f = f;
    unsigned r = v.u + 0x7fffu + ((v.u >> 16) & 1u);   // RNE
    return (unsigned short)(r >> 16);
}

static __device__ __forceinline__ f32x4 mfma16(short8v a, short8v b, f32x4 c) {
    return __builtin_amdgcn_mfma_f32_16x16x32_bf16(a, b, c, 0, 0, 0);
}

// 32x32 output tile, 1 wave. out[row,col] = sum_k A[row,k]*B[col,k] (both row-major).
static __device__ __forceinline__ void gemm_tile32(
    const unsigned short* pa0, const unsigned short* pb0,
    long sA, long sB, int K, f32x4 acc[4])
{
    const unsigned short* pa1 = pa0 + 16 * sA;
    const unsigned short* pb1 = pb0 + 16 * sB;
    #pragma unroll 4
    for (int k = 0; k < K; k += 32) {
        const short8v a0 = *(const short8v*)(pa0 + k);
        const short8v a1 = *(const short8v*)(pa1 + k);
        const short8v b0 = *(const short8v*)(pb0 + k);
        const short8v b1 = *(const short8v*)(pb1 + k);
        acc[0] = mfma16(a0, b0, acc[0]);
        acc[1] = mfma16(a0, b1, acc[1]);
        acc[2] = mfma16(a1, b0, acc[2]);
        acc[3] = mfma16(a1, b1, acc[3]);
    }
}

// ---------------------------------------------------------------------------
// y<256 : pure streaming cast x fp32 -> Xb bf16 (4096 elems per block)
// y>=256: W* fp32 -> Wrow[wi] row-major bf16 and Wtr[wi] transposed bf16
__global__ __launch_bounds__(256) void convert_kernel(
    const float* __restrict__ X,
    const float* __restrict__ Wq, const float* __restrict__ Wk,
    const float* __restrict__ Wv, const float* __restrict__ Wo,
    unsigned short* __restrict__ Xb,
    unsigned short* __restrict__ Wrow, unsigned short* __restrict__ Wtr)
{
    __shared__ unsigned short Ls[64][66];
    const int t = threadIdx.x;
    if (blockIdx.y < 256) {
        const long base = ((long)blockIdx.y * 4 + blockIdx.x) * 4096;
        #pragma unroll
        for (int p = 0; p < 4; ++p) {
            const long idx = base + p * 1024 + t * 4;
            const float4 v = *(const float4*)(X + idx);
            ushort4 o;
            o.x = f2bf(v.x); o.y = f2bf(v.y); o.z = f2bf(v.z); o.w = f2bf(v.w);
            *(ushort4*)(Xb + idx) = o;
        }
        return;
    }
    const int e0 = blockIdx.x * 64;
    const int lr = t >> 2;
    const int lc = (t & 3) * 16;
    const int wy = blockIdx.y - 256;
    const int wi = wy >> 2, rt = wy & 3;
    const float* W = (wi == 0) ? Wq : (wi == 1) ? Wk : (wi == 2) ? Wv : Wo;
    const float* src = W + (long)(rt * 64 + lr) * E + e0 + lc;
    unsigned short* drow = Wrow + (long)wi * 65536 + (long)(rt * 64 + lr) * E + e0 + lc;
    unsigned short* dtr  = Wtr  + (long)wi * 65536 + (long)(e0 + lr) * E + rt * 64 + lc;
    short8v v0, v1;
    #pragma unroll
    for (int q = 0; q < 4; ++q) {
        const float4 v = *(const float4*)(src + q * 4);
        const unsigned short b0 = f2bf(v.x), b1 = f2bf(v.y), b2 = f2bf(v.z), b3 = f2bf(v.w);
        Ls[lc + q*4 + 0][lr] = b0; Ls[lc + q*4 + 1][lr] = b1;
        Ls[lc + q*4 + 2][lr] = b2; Ls[lc + q*4 + 3][lr] = b3;
        if (q < 2) { v0[q*4+0]=(short)b0; v0[q*4+1]=(short)b1; v0[q*4+2]=(short)b2; v0[q*4+3]=(short)b3; }
        else { v1[(q-2)*4+0]=(short)b0; v1[(q-2)*4+1]=(short)b1; v1[(q-2)*4+2]=(short)b2; v1[(q-2)*4+3]=(short)b3; }
    }
    *(short8v*)(drow)     = v0;
    *(short8v*)(drow + 8) = v1;
    __syncthreads();
    short8v w0, w1;
    #pragma unroll
    for (int j = 0; j < 8; ++j) { w0[j] = (short)Ls[lr][lc + j]; w1[j] = (short)Ls[lr][lc + 8 + j]; }
    *(short8v*)(dtr)     = w0;
    *(short8v*)(dtr + 8) = w1;
}

// ---------------------------------------------------------------------------
// y==0: P  = Wq^T Wk   (A=WqT, B=WkT), bf16 out
// y==1: Rt = Wo Wv     (A=Wo row, B=WvT), bf16 out
// grid (16, 2); wave per 32x32 tile.
__global__ __launch_bounds__(256) void pr_kernel(
    const unsigned short* __restrict__ Wrow, const unsigned short* __restrict__ Wtr,
    unsigned short* __restrict__ P, unsigned short* __restrict__ Rt)
{
    const int lane = threadIdx.x & 63;
    const int lr = lane & 15, lg = lane >> 4;
    const int w  = blockIdx.x * 4 + (threadIdx.x >> 6);
    const int ti = w >> 3, tj = w & 7;
    const int mode = blockIdx.y;
    const unsigned short* A = (mode == 0) ? Wtr           : (Wrow + 3 * 65536);
    const unsigned short* B = (mode == 0) ? (Wtr + 65536) : (Wtr + 2 * 65536);
    f32x4 acc[4] = {};
    gemm_tile32(A + (long)(ti * 32 + lr) * E + lg * 8,
                B + (long)(tj * 32 + lr) * E + lg * 8, E, E, E, acc);
    unsigned short* out = (mode == 0) ? P : Rt;
    #pragma unroll
    for (int q = 0; q < 4; ++q) {
        const int qr = q >> 1, qc = q & 1;
        #pragma unroll
        for (int r = 0; r < 4; ++r)
            out[(ti * 32 + qr * 16 + lg * 4 + r) * E + tj * 32 + qc * 16 + lr] = f2bf(acc[q][r]);
    }
}

// ---------------------------------------------------------------------------
// Gram partials from Xb via LDS-staged panel transpose.
// grid (4 strips, 4 batches, 16 z). Block: 256 thr (4 waves).
// z-chunk = 256 s-rows, processed as 2 panels of 128.
// Panel: Pl[e][ss] = Xb[s0+ss][e]  (e 0..255, ss 0..127), stride 136 (272B rows).
// Wave w computes 64x64 tile: rows [st*64, +64), cols [w*64, +64).
__global__ __launch_bounds__(256) void gram_kernel(
    const unsigned short* __restrict__ Xb, float* __restrict__ Gp)
{
    __shared__ unsigned short Pl[256][136];
    const int st = blockIdx.x;     // strip: G rows [st*64, +64)
    const int b  = blockIdx.y;
    const int z  = blockIdx.z;     // s-chunk of 256
    const int t = threadIdx.x;
    const int w = t >> 6, lane = t & 63, lr = lane & 15, lg = lane >> 4;
    f32x4 acc[4][4] = {};          // [rowgrp 16][colgrp 16]
    const unsigned short* xbase = Xb + ((long)b * S + z * 256) * E;
    #pragma unroll 1
    for (int p = 0; p < 2; ++p) {
        const unsigned short* src = xbase + p * 128 * E;
        #pragma unroll
        for (int i = 0; i < 8; ++i) {
            const int flat = i * 4096 + t * 16;
            const int row = flat >> 8;          // ss
            const int col = flat & 255;         // e
            const short8v u0 = *(const short8v*)(src + flat);
            const short8v u1 = *(const short8v*)(src + flat + 8);
            #pragma unroll
            for (int j = 0; j < 8; ++j) {
                Pl[col + j][row]     = (unsigned short)u0[j];
                Pl[col + 8 + j][row] = (unsigned short)u1[j];
            }
        }
        __syncthreads();
        const unsigned short* A0 = &Pl[st * 64 + lr][lg * 8];
        const unsigned short* B0 = &Pl[w  * 64 + lr][lg * 8];
        #pragma unroll
        for (int k = 0; k < 128; k += 32) {
            short8v a[4], bb[4];
            #pragma unroll
            for (int q = 0; q < 4; ++q) {
                a[q]  = *(const short8v*)(A0 + (long)(q * 16) * 136 + k);
                bb[q] = *(const short8v*)(B0 + (long)(q * 16) * 136 + k);
            }
            #pragma unroll
            for (int i = 0; i < 4; ++i)
                #pragma unroll
                for (int j = 0; j < 4; ++j)
                    acc[i][j] = mfma16(a[i], bb[j], acc[i][j]);
        }
        __syncthreads();
    }
    float* out = Gp + (((long)b * 16 + z) << 16);
    #pragma unroll
    for (int i = 0; i < 4; ++i)
        #pragma unroll
        for (int j = 0; j < 4; ++j)
            #pragma unroll
            for (int r = 0; r < 4; ++r)
                out[(st * 64 + i * 16 + lg * 4 + r) * E + w * 64 + j * 16 + lr] = acc[i][j][r];
}

// ---------------------------------------------------------------------------
// G[b] bf16 = sum_c Gp[b][c] (16 fp32 chunk partials)
__global__ __launch_bounds__(256) void reduce_g_kernel(
    const float* __restrict__ Gp, unsigned short* __restrict__ G)
{
    const long i = ((long)blockIdx.x * 256 + threadIdx.x) * 4;   // [0, 262144)
    const long b = i >> 16;
    const long off = i & 65535;
    float4 s = make_float4(0.f, 0.f, 0.f, 0.f);
    #pragma unroll
    for (long c = 0; c < 16; ++c) {
        const float4 v = *(const float4*)(Gp + ((b * 16 + c) << 16) + off);
        s.x += v.x; s.y += v.y; s.z += v.z; s.w += v.w;
    }
    ushort4 o;
    o.x = f2bf(s.x); o.y = f2bf(s.y); o.z = f2bf(s.z); o.w = f2bf(s.w);
    *(ushort4*)(G + i) = o;
}

// ---------------------------------------------------------------------------
// grid (4 i0-bands, 4 batches, 4 g-slices), 256 threads (4 waves).
// Stage 1 (duplicated across g-slices): Tband = P[i0:i0+64,:] @ G_b -> LDS bf16.
// Stage 2: MT[b][g0:g0+64][i0:i0+64] = 1e-11 * Rt[g0:,:] @ Tband^T.
__global__ __launch_bounds__(256) void tm_kernel(
    const unsigned short* __restrict__ P, const unsigned short* __restrict__ G,
    const unsigned short* __restrict__ Rt, unsigned short* __restrict__ MT)
{
    __shared__ unsigned short Ts[64][264];
    const int b  = blockIdx.y;
    const int i0 = blockIdx.x * 64;
    const int g0 = blockIdx.z * 64;
    const int w    = threadIdx.x >> 6;
    const int lane = threadIdx.x & 63;
    const int lr = lane & 15, lg = lane >> 4;
    {   // stage 1
        const int tr = w >> 1;
        const unsigned short* pa = P + (long)(i0 + tr * 32 + lr) * E + lg * 8;
        #pragma unroll
        for (int j = 0; j < 4; ++j) {
            const int tc = (w & 1) * 4 + j;
            f32x4 acc[4] = {};
            gemm_tile32(pa, G + ((long)b << 16) + (long)(tc * 32 + lr) * E + lg * 8,
                        E, E, E, acc);
            #pragma unroll
            for (int q = 0; q < 4; ++q) {
                const int qr = q >> 1, qc = q & 1;
                #pragma unroll
                for (int r = 0; r < 4; ++r)
                    Ts[tr * 32 + qr * 16 + lg * 4 + r][tc * 32 + qc * 16 + lr] = f2bf(acc[q][r]);
            }
        }
    }
    __syncthreads();
    {   // stage 2
        const int tg = w >> 1, te = w & 1;
        f32x4 acc[4] = {};
        gemm_tile32(Rt + (long)(g0 + tg * 32 + lr) * E + lg * 8,
                    &Ts[te * 32 + lr][lg * 8], E, 264, E, acc);
        unsigned short* out = MT + ((long)b << 16);
        #pragma unroll
        for (int q = 0; q < 4; ++q) {
            const int qr = q >> 1, qc = q & 1;
            #pragma unroll
            for (int r = 0; r < 4; ++r) {
                const int g = g0 + tg * 32 + qr * 16 + lg * 4 + r;
                const int e = te * 32 + qc * 16 + lr;
                out[g * E + i0 + e] = f2bf(acc[q][r] * 1e-11f);
            }
        }
    }
}

// ---------------------------------------------------------------------------
// out = Xb @ M_b. Block = 32 s-rows; 4 waves share the A rows, each wave owns
// one 64-wide g-tile (g0 = w*64). grid = 512 blocks.
__global__ __launch_bounds__(256) void final_kernel(
    const unsigned short* __restrict__ Xb, const unsigned short* __restrict__ MT,
    float* __restrict__ Out)
{
    const int s0 = blockIdx.x * 32;
    const int b  = s0 >> 12;
    const int w    = threadIdx.x >> 6;
    const int g0 = w * 64;
    const int lane = threadIdx.x & 63;
    const int lr = lane & 15, lg = lane >> 4;
    const unsigned short* pa0 = Xb + (long)(s0 + lr) * E + lg * 8;
    const unsigned short* pa1 = pa0 + 16 * E;
    const unsigned short* pb  = MT + ((long)b * E + g0 + lr) * E + lg * 8;
    f32x4 acc[2][4] = {};
    #pragma unroll
    for (int k = 0; k < E; k += 32) {
        const short8v a0 = *(const short8v*)(pa0 + k);
        const short8v a1 = *(const short8v*)(pa1 + k);
        #pragma unroll
        for (int ni = 0; ni < 4; ++ni) {
            const short8v bf = *(const short8v*)(pb + (long)ni * 16 * E + k);
            acc[0][ni] = mfma16(a0, bf, acc[0][ni]);
            acc[1][ni] = mfma16(a1, bf, acc[1][ni]);
        }
    }
    #pragma unroll
    for (int mi = 0; mi < 2; ++mi)
        #pragma unroll
        for (int r = 0; r < 4; ++r) {
            float* row = Out + (long)(s0 + mi * 16 + lg * 4 + r) * E + g0 + lr;
            #pragma unroll
            for (int ni = 0; ni < 4; ++ni) row[ni * 16] = acc[mi][ni][r];
        }
}

// ---------------------------------------------------------------------------
extern "C" void kernel_launch(void* const* d_in, const int* in_sizes, int n_in,
                              void* d_out, int out_size, void* d_ws, size_t ws_size,
                              hipStream_t stream)
{
    const float* x  = (const float*)d_in[0];
    const float* Wq = (const float*)d_in[1];
    const float* Wk = (const float*)d_in[2];
    const float* Wv = (const float*)d_in[3];
    const float* Wo = (const float*)d_in[4];
    float* out = (float*)d_out;

    char* ws = (char*)d_ws;
    unsigned short* Xb   = (unsigned short*)(ws);                 //  8.39 MB
    unsigned short* Wrow = (unsigned short*)(ws + 8388608);       //  0.52 MB
    unsigned short* Wtr  = (unsigned short*)(ws + 8912896);       //  0.52 MB
    float*          Gp   = (float*)(ws + 9437184);                // 16.78 MB (16 fp32 partials x 4 b)
    unsigned short* G    = (unsigned short*)(ws + 26214400);      //  0.52 MB
    unsigned short* P    = (unsigned short*)(ws + 26738688);      //  0.13 MB
    unsigned short* Rt   = (unsigned short*)(ws + 26869760);      //  0.13 MB
    unsigned short* MT   = (unsigned short*)(ws + 27000832);      //  0.52 MB (ends ~27.5 MB)

    convert_kernel <<<dim3(4, 272),   dim3(256), 0, stream>>>(x, Wq, Wk, Wv, Wo, Xb, Wrow, Wtr);
    pr_kernel      <<<dim3(16, 2),    dim3(256), 0, stream>>>(Wrow, Wtr, P, Rt);
    gram_kernel    <<<dim3(4, 4, 16), dim3(256), 0, stream>>>(Xb, Gp);
    reduce_g_kernel<<<dim3(256),      dim3(256), 0, stream>>>(Gp, G);
    tm_kernel      <<<dim3(4, 4, 4),  dim3(256), 0, stream>>>(P, G, Rt, MT);
    final_kernel   <<<dim3(512),      dim3(256), 0, stream>>>(Xb, MT, out);
}